// Round 1
// baseline (672.610 us; speedup 1.0000x reference)
//
#include <hip/hip_runtime.h>
#include <hip/hip_bf16.h>
#include <cstddef>

#define B_ 2
#define D_ 12
#define H_ 200
#define W_ 200
#define CELLS_ (B_ * D_ * H_ * W_)   // 960000
#define N_ 60000
#define CIN_ 2
#define COUT_ 64
#define K27 27
#define EPS_ 1e-5f

// ---------------------------------------------------------------------------
// Kernel 1: scatter conv. One 64-lane wave per (k, n) scatter entry.
// lane c handles channel c: contrib = f0*W[k][0][c] + f1*W[k][1][c]
// atomicAdd into out[idx*64 + c]; lane 0 marks the cell active.
// Entry index is wave-uniform -> the sentinel branch is non-divergent.
// ---------------------------------------------------------------------------
__global__ void scatter_conv_kernel(const float* __restrict__ feat,
                                    const float* __restrict__ weight,
                                    const int* __restrict__ scatter,
                                    float* __restrict__ out,
                                    unsigned char* __restrict__ active) {
    int gid = blockIdx.x * blockDim.x + threadIdx.x;
    int entry = gid >> 6;          // one wave per entry
    int c = gid & 63;              // channel
    if (entry >= K27 * N_) return;

    int idx = scatter[entry];      // wave-uniform load
    if (idx >= CELLS_) return;     // OOB sentinel, wave-uniform

    int k = entry / N_;
    int n = entry - k * N_;

    float f0 = feat[n * CIN_ + 0];
    float f1 = feat[n * CIN_ + 1];
    float w0 = weight[(k * CIN_ + 0) * COUT_ + c];
    float w1 = weight[(k * CIN_ + 1) * COUT_ + c];
    float contrib = f0 * w0 + f1 * w1;

    atomicAdd(&out[(size_t)idx * COUT_ + c], contrib);
    if (c == 0) active[idx] = 1;
}

// ---------------------------------------------------------------------------
// Kernel 2: LayerNorm + ReLU, in place on out. 16 lanes per cell, float4
// per lane (16B). Reduce sum and sumsq across the 16-lane group via
// __shfl_xor, then normalize. Inactive cells -> 0.
// ---------------------------------------------------------------------------
__global__ void ln_relu_kernel(const float* __restrict__ gamma,
                               const float* __restrict__ beta,
                               float* __restrict__ out,
                               const unsigned char* __restrict__ active) {
    int tid = blockIdx.x * blockDim.x + threadIdx.x;
    int cell = tid >> 4;           // 16 lanes per cell
    int q = tid & 15;              // quad index: channels [q*4, q*4+4)
    if (cell >= CELLS_) return;

    size_t base = (size_t)cell * COUT_ + q * 4;
    float4 x = *reinterpret_cast<const float4*>(&out[base]);

    float s  = x.x + x.y + x.z + x.w;
    float s2 = x.x * x.x + x.y * x.y + x.z * x.z + x.w * x.w;

    // reduce across 16-lane group
    #pragma unroll
    for (int m = 1; m < 16; m <<= 1) {
        s  += __shfl_xor(s,  m, 16);
        s2 += __shfl_xor(s2, m, 16);
    }

    float mu  = s * (1.0f / COUT_);
    float var = s2 * (1.0f / COUT_) - mu * mu;
    float inv = rsqrtf(var + EPS_);

    float4 g = *reinterpret_cast<const float4*>(&gamma[q * 4]);
    float4 b = *reinterpret_cast<const float4*>(&beta[q * 4]);

    float4 r;
    if (active[cell]) {
        r.x = fmaxf((x.x - mu) * inv * g.x + b.x, 0.0f);
        r.y = fmaxf((x.y - mu) * inv * g.y + b.y, 0.0f);
        r.z = fmaxf((x.z - mu) * inv * g.z + b.z, 0.0f);
        r.w = fmaxf((x.w - mu) * inv * g.w + b.w, 0.0f);
    } else {
        r.x = r.y = r.z = r.w = 0.0f;
    }
    *reinterpret_cast<float4*>(&out[base]) = r;
}

extern "C" void kernel_launch(void* const* d_in, const int* in_sizes, int n_in,
                              void* d_out, int out_size, void* d_ws, size_t ws_size,
                              hipStream_t stream) {
    const float* feat    = (const float*)d_in[0];   // (N, 2)
    const float* weight  = (const float*)d_in[1];   // (27, 2, 64)
    const float* gamma   = (const float*)d_in[2];   // (64,)
    const float* beta    = (const float*)d_in[3];   // (64,)
    const int*   scatter = (const int*)d_in[4];     // (27, N)

    float* out = (float*)d_out;                     // (CELLS, 64) accumulator + result
    unsigned char* active = (unsigned char*)d_ws;   // CELLS bytes

    // zero-init accumulator and flags (ws/out are poisoned 0xAA before each run)
    hipMemsetAsync(out, 0, (size_t)out_size * sizeof(float), stream);
    hipMemsetAsync(active, 0, CELLS_, stream);

    // scatter conv: 27*N entries, 64 threads (one wave) each
    {
        long long total = (long long)K27 * N_ * 64;     // 103,680,000
        int block = 256;
        int grid = (int)((total + block - 1) / block);
        scatter_conv_kernel<<<grid, block, 0, stream>>>(feat, weight, scatter, out, active);
    }

    // layernorm + relu: 16 threads per cell
    {
        long long total = (long long)CELLS_ * 16;       // 15,360,000
        int block = 256;
        int grid = (int)((total + block - 1) / block);
        ln_relu_kernel<<<grid, block, 0, stream>>>(gamma, beta, out, active);
    }
}

// Round 2
// 464.579 us; speedup vs baseline: 1.4478x; 1.4478x over previous
//
#include <hip/hip_runtime.h>
#include <hip/hip_bf16.h>
#include <cstddef>
#include <cstdint>

#define B_ 2
#define D_ 12
#define H_ 200
#define W_ 200
#define CELLS_ (B_ * D_ * H_ * W_)   // 960000
#define N_ 60000
#define CIN_ 2
#define COUT_ 64
#define K27 27
#define EPS_ 1e-5f

// ===========================================================================
// FAST PATH: inverted-index gather
// ===========================================================================

// Kernel A: build inverted index. One thread per (k,n) scatter entry.
// pos = atomicAdd(count[idx]); slots[pos*CELLS + idx] = entry_id.
// Transposed slot layout -> gather kernel reads are coalesced.
__global__ void build_index_kernel(const int* __restrict__ scatter,
                                   int* __restrict__ count,
                                   uint32_t* __restrict__ slots) {
    int gid = blockIdx.x * blockDim.x + threadIdx.x;
    if (gid >= K27 * N_) return;
    int idx = scatter[gid];
    if (idx >= CELLS_) return;            // OOB sentinel
    int pos = atomicAdd(&count[idx], 1);  // pos < 27 guaranteed (injective per k)
    slots[(size_t)pos * CELLS_ + idx] = (uint32_t)gid;
}

// Kernel B: fused gather-conv + LayerNorm + ReLU. 16 lanes per cell,
// float4 (4 channels) per lane. Each cell's output written exactly once.
__global__ void gather_ln_kernel(const float* __restrict__ feat,
                                 const float* __restrict__ weight,
                                 const float* __restrict__ gamma,
                                 const float* __restrict__ beta,
                                 const int* __restrict__ count,
                                 const uint32_t* __restrict__ slots,
                                 float* __restrict__ out) {
    int tid = blockIdx.x * blockDim.x + threadIdx.x;
    int cell = tid >> 4;                  // 16 lanes per cell
    int q = tid & 15;                     // channels [4q, 4q+4)
    if (cell >= CELLS_) return;

    int cnt = count[cell];
    size_t obase = (size_t)cell * COUT_ + q * 4;

    if (cnt == 0) {                       // inactive -> exact zeros
        float4 z = {0.f, 0.f, 0.f, 0.f};
        *reinterpret_cast<float4*>(&out[obase]) = z;
        return;
    }

    float4 acc = {0.f, 0.f, 0.f, 0.f};
    for (int e = 0; e < cnt; ++e) {
        uint32_t ent = slots[(size_t)e * CELLS_ + cell];  // coalesced across cells
        uint32_t k = ent / (uint32_t)N_;                  // magic-mul division
        uint32_t n = ent - k * (uint32_t)N_;
        float2 f = *reinterpret_cast<const float2*>(&feat[n * CIN_]);
        // weight[k][0][4q..4q+3] and weight[k][1][4q..4q+3] -- 13.8 KB, L1-resident
        const float* wk = &weight[(size_t)k * CIN_ * COUT_];
        float4 w0 = *reinterpret_cast<const float4*>(&wk[q * 4]);
        float4 w1 = *reinterpret_cast<const float4*>(&wk[COUT_ + q * 4]);
        acc.x += f.x * w0.x + f.y * w1.x;
        acc.y += f.x * w0.y + f.y * w1.y;
        acc.z += f.x * w0.z + f.y * w1.z;
        acc.w += f.x * w0.w + f.y * w1.w;
    }

    // LayerNorm over 64 channels: reduce across the 16-lane group
    float s  = acc.x + acc.y + acc.z + acc.w;
    float s2 = acc.x * acc.x + acc.y * acc.y + acc.z * acc.z + acc.w * acc.w;
    #pragma unroll
    for (int m = 1; m < 16; m <<= 1) {
        s  += __shfl_xor(s,  m, 16);
        s2 += __shfl_xor(s2, m, 16);
    }
    float mu  = s * (1.0f / COUT_);
    float var = s2 * (1.0f / COUT_) - mu * mu;
    float inv = rsqrtf(var + EPS_);

    float4 g = *reinterpret_cast<const float4*>(&gamma[q * 4]);
    float4 b = *reinterpret_cast<const float4*>(&beta[q * 4]);

    float4 r;
    r.x = fmaxf((acc.x - mu) * inv * g.x + b.x, 0.0f);
    r.y = fmaxf((acc.y - mu) * inv * g.y + b.y, 0.0f);
    r.z = fmaxf((acc.z - mu) * inv * g.z + b.z, 0.0f);
    r.w = fmaxf((acc.w - mu) * inv * g.w + b.w, 0.0f);
    *reinterpret_cast<float4*>(&out[obase]) = r;
}

// ===========================================================================
// FALLBACK PATH (round-1 kernels) if ws_size is too small for the index
// ===========================================================================

__global__ void scatter_conv_kernel(const float* __restrict__ feat,
                                    const float* __restrict__ weight,
                                    const int* __restrict__ scatter,
                                    float* __restrict__ out,
                                    unsigned char* __restrict__ active) {
    int gid = blockIdx.x * blockDim.x + threadIdx.x;
    int entry = gid >> 6;
    int c = gid & 63;
    if (entry >= K27 * N_) return;
    int idx = scatter[entry];
    if (idx >= CELLS_) return;
    int k = entry / N_;
    int n = entry - k * N_;
    float f0 = feat[n * CIN_ + 0];
    float f1 = feat[n * CIN_ + 1];
    float w0 = weight[(k * CIN_ + 0) * COUT_ + c];
    float w1 = weight[(k * CIN_ + 1) * COUT_ + c];
    atomicAdd(&out[(size_t)idx * COUT_ + c], f0 * w0 + f1 * w1);
    if (c == 0) active[idx] = 1;
}

__global__ void ln_relu_kernel(const float* __restrict__ gamma,
                               const float* __restrict__ beta,
                               float* __restrict__ out,
                               const unsigned char* __restrict__ active) {
    int tid = blockIdx.x * blockDim.x + threadIdx.x;
    int cell = tid >> 4;
    int q = tid & 15;
    if (cell >= CELLS_) return;
    size_t base = (size_t)cell * COUT_ + q * 4;
    float4 x = *reinterpret_cast<const float4*>(&out[base]);
    float s  = x.x + x.y + x.z + x.w;
    float s2 = x.x * x.x + x.y * x.y + x.z * x.z + x.w * x.w;
    #pragma unroll
    for (int m = 1; m < 16; m <<= 1) {
        s  += __shfl_xor(s,  m, 16);
        s2 += __shfl_xor(s2, m, 16);
    }
    float mu  = s * (1.0f / COUT_);
    float var = s2 * (1.0f / COUT_) - mu * mu;
    float inv = rsqrtf(var + EPS_);
    float4 g = *reinterpret_cast<const float4*>(&gamma[q * 4]);
    float4 b = *reinterpret_cast<const float4*>(&beta[q * 4]);
    float4 r;
    if (active[cell]) {
        r.x = fmaxf((x.x - mu) * inv * g.x + b.x, 0.0f);
        r.y = fmaxf((x.y - mu) * inv * g.y + b.y, 0.0f);
        r.z = fmaxf((x.z - mu) * inv * g.z + b.z, 0.0f);
        r.w = fmaxf((x.w - mu) * inv * g.w + b.w, 0.0f);
    } else {
        r.x = r.y = r.z = r.w = 0.0f;
    }
    *reinterpret_cast<float4*>(&out[base]) = r;
}

extern "C" void kernel_launch(void* const* d_in, const int* in_sizes, int n_in,
                              void* d_out, int out_size, void* d_ws, size_t ws_size,
                              hipStream_t stream) {
    const float* feat    = (const float*)d_in[0];   // (N, 2)
    const float* weight  = (const float*)d_in[1];   // (27, 2, 64)
    const float* gamma   = (const float*)d_in[2];   // (64,)
    const float* beta    = (const float*)d_in[3];   // (64,)
    const int*   scatter = (const int*)d_in[4];     // (27, N)
    float* out = (float*)d_out;                     // (CELLS, 64)

    const size_t count_bytes = (size_t)CELLS_ * sizeof(int);
    const size_t slots_bytes = (size_t)CELLS_ * K27 * sizeof(uint32_t);

    if (ws_size >= count_bytes + slots_bytes) {
        // ---- fast path: inverted index + fused gather ----
        int* count = (int*)d_ws;
        uint32_t* slots = (uint32_t*)((char*)d_ws + count_bytes);

        hipMemsetAsync(count, 0, count_bytes, stream);

        {
            int total = K27 * N_;                       // 1,620,000
            int block = 256;
            int grid = (total + block - 1) / block;
            build_index_kernel<<<grid, block, 0, stream>>>(scatter, count, slots);
        }
        {
            long long total = (long long)CELLS_ * 16;   // 15,360,000
            int block = 256;
            int grid = (int)((total + block - 1) / block);
            gather_ln_kernel<<<grid, block, 0, stream>>>(feat, weight, gamma, beta,
                                                         count, slots, out);
        }
    } else {
        // ---- fallback: atomic scatter + separate LN ----
        unsigned char* active = (unsigned char*)d_ws;
        hipMemsetAsync(out, 0, (size_t)out_size * sizeof(float), stream);
        hipMemsetAsync(active, 0, CELLS_, stream);
        {
            long long total = (long long)K27 * N_ * 64;
            int block = 256;
            int grid = (int)((total + block - 1) / block);
            scatter_conv_kernel<<<grid, block, 0, stream>>>(feat, weight, scatter, out, active);
        }
        {
            long long total = (long long)CELLS_ * 16;
            int block = 256;
            int grid = (int)((total + block - 1) / block);
            ln_relu_kernel<<<grid, block, 0, stream>>>(gamma, beta, out, active);
        }
    }
}

// Round 3
// 400.493 us; speedup vs baseline: 1.6795x; 1.1600x over previous
//
#include <hip/hip_runtime.h>
#include <hip/hip_bf16.h>
#include <cstddef>
#include <cstdint>

#define B_ 2
#define D_ 12
#define H_ 200
#define W_ 200
#define HW_ (H_ * W_)
#define DHW_ (D_ * H_ * W_)
#define CELLS_ (B_ * D_ * H_ * W_)   // 960000
#define N_ 60000
#define CIN_ 2
#define COUT_ 64
#define K27 27
#define EPS_ 1e-5f

// ---------------------------------------------------------------------------
// Kernel A: build dense cell -> point_id map.
// scatter[13][n] is the identity tap (fz,fy,fx)=(1,1,1): oz=z,oy=y,ox=x,
// i.e. point n's own linear cell index, always in-bounds. map is pre-set
// to -1 via memset(0xFF).
// ---------------------------------------------------------------------------
__global__ void fill_map_kernel(const int* __restrict__ scatter,
                                int* __restrict__ map) {
    int n = blockIdx.x * blockDim.x + threadIdx.x;
    if (n >= N_) return;
    map[scatter[13 * N_ + n]] = n;
}

// ---------------------------------------------------------------------------
// Kernel B: fused stencil-gather conv + LayerNorm + ReLU.
// One 64-lane wave per output cell; lane c owns channel c.
//   1. lanes 0..26 probe the 27 neighbor cells in the map (L1-heavy reuse)
//   2. ballot -> iterate only over actual contributors (avg 1.69 per cell)
//   3. per hit: broadcast feat[n] (shfl), 2 FMAs vs L1-resident weight
//   4. width-64 shuffle reduction for LN, ReLU, one coalesced 256B store
// A point at p contributes to cell c iff p = c + (f-1), using weight[k=l].
// ---------------------------------------------------------------------------
__global__ __launch_bounds__(256) void gather_cell_kernel(
        const float* __restrict__ feat,
        const float* __restrict__ weight,
        const float* __restrict__ gamma,
        const float* __restrict__ beta,
        const int* __restrict__ map,
        float* __restrict__ out) {
    int wid = (blockIdx.x * blockDim.x + threadIdx.x) >> 6;   // one wave per cell
    int lane = threadIdx.x & 63;
    if (wid >= CELLS_) return;
    int cell = wid;

    // decode cell -> (b, z, y, x); wave-uniform
    int b = cell / DHW_;
    int r = cell - b * DHW_;
    int z = r / HW_;        r -= z * HW_;
    int y = r / W_;
    int x = r - y * W_;

    // probe the 27 stencil neighbors (lanes 0..26)
    int n = -1;
    if (lane < K27) {
        int fz = lane / 9;
        int t  = lane - fz * 9;
        int fy = t / 3;
        int fx = t - fy * 3;
        int pz = z + fz - 1;
        int py = y + fy - 1;
        int px = x + fx - 1;
        if (pz >= 0 && pz < D_ && py >= 0 && py < H_ && px >= 0 && px < W_)
            n = map[((b * D_ + pz) * H_ + py) * W_ + px];
    }

    unsigned long long mask = __ballot(n >= 0);
    size_t obase = (size_t)cell * COUT_ + lane;

    if (mask == 0ull) {                 // inactive cell -> exact zeros
        out[obase] = 0.0f;
        return;
    }

    float acc = 0.0f;
    while (mask) {
        int l = __ffsll((long long)mask) - 1;   // stencil index == weight k
        mask &= mask - 1;
        int nn = __shfl(n, l, 64);              // wave-uniform point id
        float f0 = feat[nn * CIN_ + 0];         // broadcast loads (L1/L2)
        float f1 = feat[nn * CIN_ + 1];
        const float* wk = &weight[(size_t)l * CIN_ * COUT_];
        acc += f0 * wk[lane] + f1 * wk[COUT_ + lane];
    }

    // LayerNorm across the 64 channels (full-wave butterfly)
    float s  = acc;
    float s2 = acc * acc;
    #pragma unroll
    for (int m = 1; m < 64; m <<= 1) {
        s  += __shfl_xor(s,  m, 64);
        s2 += __shfl_xor(s2, m, 64);
    }
    float mu  = s * (1.0f / COUT_);
    float var = s2 * (1.0f / COUT_) - mu * mu;
    float inv = rsqrtf(var + EPS_);

    float rr = fmaxf((acc - mu) * inv * gamma[lane] + beta[lane], 0.0f);
    out[obase] = rr;
}

extern "C" void kernel_launch(void* const* d_in, const int* in_sizes, int n_in,
                              void* d_out, int out_size, void* d_ws, size_t ws_size,
                              hipStream_t stream) {
    const float* feat    = (const float*)d_in[0];   // (N, 2)
    const float* weight  = (const float*)d_in[1];   // (27, 2, 64)
    const float* gamma   = (const float*)d_in[2];   // (64,)
    const float* beta    = (const float*)d_in[3];   // (64,)
    const int*   scatter = (const int*)d_in[4];     // (27, N)
    float* out = (float*)d_out;                     // (CELLS, 64)

    int* map = (int*)d_ws;                          // CELLS * 4 B = 3.84 MB

    // map := -1 everywhere (0xFF bytes), then 60k point-id writes
    hipMemsetAsync(map, 0xFF, (size_t)CELLS_ * sizeof(int), stream);
    {
        int block = 256;
        int grid = (N_ + block - 1) / block;
        fill_map_kernel<<<grid, block, 0, stream>>>(scatter, map);
    }

    // fused gather-conv + LN + ReLU: one wave per cell
    {
        long long total = (long long)CELLS_ * 64;   // 61,440,000 threads
        int block = 256;
        int grid = (int)((total + block - 1) / block);
        gather_cell_kernel<<<grid, block, 0, stream>>>(feat, weight, gamma, beta,
                                                       map, out);
    }
}

// Round 4
// 308.576 us; speedup vs baseline: 2.1797x; 1.2979x over previous
//
#include <hip/hip_runtime.h>
#include <hip/hip_bf16.h>
#include <cstddef>
#include <cstdint>

#define B_ 2
#define D_ 12
#define H_ 200
#define W_ 200
#define HW_ (H_ * W_)
#define DHW_ (D_ * H_ * W_)
#define CELLS_ (B_ * D_ * H_ * W_)   // 960000
#define N_ 60000
#define CIN_ 2
#define COUT_ 64
#define K27 27
#define EPS_ 1e-5f

// ---------------------------------------------------------------------------
// Kernel A: dense cell -> point_id map. scatter[13][n] is the identity tap
// (fz,fy,fx)=(1,1,1) = point n's own cell, always in-bounds. map pre-set to
// -1 via memset(0xFF). (Verified correct in rounds 2-3.)
// ---------------------------------------------------------------------------
__global__ void fill_map_kernel(const int* __restrict__ scatter,
                                int* __restrict__ map) {
    int n = blockIdx.x * blockDim.x + threadIdx.x;
    if (n >= N_) return;
    map[scatter[13 * N_ + n]] = n;
}

// ---------------------------------------------------------------------------
// Kernel B: fused stencil-gather conv + LayerNorm + ReLU.
// 16 lanes per cell, float4 (4 channels) per lane, 4 cells per wave.
// Grid: x = 16 cells/block along W, y = H rows, z = b*D+z planes.
//   - probe 27 taps in 2 rounds of 16 lanes; per-group 27-bit hit mask
//     extracted from two 64-bit ballots
//   - loop only over actual hits (avg 1.69/cell); broadcast point id via
//     shfl within the 16-lane group; 8 FMAs vs L1-resident weight per hit
//   - width-16 butterfly (8 shuffles) for LN; one float4 store per lane
// ---------------------------------------------------------------------------
__global__ __launch_bounds__(256) void gather_cell16_kernel(
        const float* __restrict__ feat,
        const float* __restrict__ weight,
        const float* __restrict__ gamma,
        const float* __restrict__ beta,
        const int* __restrict__ map,
        float* __restrict__ out) {
    const int tid = threadIdx.x;
    const int slot = tid >> 4;              // cell slot within block, 0..15
    const int q    = tid & 15;              // lane within 16-lane group
    const int gw   = slot & 3;              // group within wave, 0..3

    const int x  = blockIdx.x * 16 + slot;  // cell x
    const int y  = blockIdx.y;              // cell y
    const int bz = blockIdx.z;              // b*D + z  (0..23)
    const int b  = bz >= D_ ? 1 : 0;        // B_=2
    const int z  = bz - b * D_;

    const bool cell_ok = (x < W_);

    // ---- probe round 1: taps 0..15 (lane q probes tap q) ----
    int n1 = -1;
    {
        int fz = q / 9;
        int t  = q - fz * 9;
        int fy = t / 3;
        int fx = t - fy * 3;
        int pz = z + fz - 1, py = y + fy - 1, px = x + fx - 1;
        if (cell_ok && pz >= 0 && pz < D_ && py >= 0 && py < H_ &&
            px >= 0 && px < W_)
            n1 = map[((b * D_ + pz) * H_ + py) * W_ + px];
    }
    // ---- probe round 2: taps 16..26 (lanes 0..10 of each group) ----
    int n2 = -1;
    if (q < K27 - 16) {
        int tap = q + 16;
        int fz = tap / 9;
        int t  = tap - fz * 9;
        int fy = t / 3;
        int fx = t - fy * 3;
        int pz = z + fz - 1, py = y + fy - 1, px = x + fx - 1;
        if (cell_ok && pz >= 0 && pz < D_ && py >= 0 && py < H_ &&
            px >= 0 && px < W_)
            n2 = map[((b * D_ + pz) * H_ + py) * W_ + px];
    }

    unsigned long long ball1 = __ballot(n1 >= 0);
    unsigned long long ball2 = __ballot(n2 >= 0);
    const int shift = gw * 16;
    unsigned int mask = (unsigned int)((ball1 >> shift) & 0xFFFFull)
                      | ((unsigned int)((ball2 >> shift) & 0x7FFull) << 16);
    const bool active = (mask != 0u);

    // ---- gather-conv over actual hits ----
    float4 acc = {0.f, 0.f, 0.f, 0.f};
    while (mask) {
        int l = __ffs(mask) - 1;            // tap index == weight k
        mask &= mask - 1;
        // source lane (same group, same wave) holds the point id
        int nn = __shfl((l < 16) ? n1 : n2, (gw << 4) + (l & 15), 64);
        float2 f = *reinterpret_cast<const float2*>(&feat[nn * CIN_]);
        const float* wk = &weight[l * (CIN_ * COUT_) + q * 4];
        float4 w0 = *reinterpret_cast<const float4*>(wk);
        float4 w1 = *reinterpret_cast<const float4*>(wk + COUT_);
        acc.x += f.x * w0.x + f.y * w1.x;
        acc.y += f.x * w0.y + f.y * w1.y;
        acc.z += f.x * w0.z + f.y * w1.z;
        acc.w += f.x * w0.w + f.y * w1.w;
    }

    // ---- LayerNorm over 64 channels: butterfly across the 16-lane group ----
    float s  = acc.x + acc.y + acc.z + acc.w;
    float s2 = acc.x * acc.x + acc.y * acc.y + acc.z * acc.z + acc.w * acc.w;
    #pragma unroll
    for (int m = 1; m < 16; m <<= 1) {
        s  += __shfl_xor(s,  m, 16);
        s2 += __shfl_xor(s2, m, 16);
    }
    float mu  = s * (1.0f / COUT_);
    float var = s2 * (1.0f / COUT_) - mu * mu;
    float inv = rsqrtf(var + EPS_);

    float4 gm = *reinterpret_cast<const float4*>(&gamma[q * 4]);
    float4 bt = *reinterpret_cast<const float4*>(&beta[q * 4]);

    float4 r;
    if (active) {
        r.x = fmaxf((acc.x - mu) * inv * gm.x + bt.x, 0.0f);
        r.y = fmaxf((acc.y - mu) * inv * gm.y + bt.y, 0.0f);
        r.z = fmaxf((acc.z - mu) * inv * gm.z + bt.z, 0.0f);
        r.w = fmaxf((acc.w - mu) * inv * gm.w + bt.w, 0.0f);
    } else {
        r.x = r.y = r.z = r.w = 0.0f;       // inactive -> exact zeros
    }

    if (cell_ok) {
        size_t obase = ((size_t)((bz * H_ + y) * W_ + x)) * COUT_ + q * 4;
        *reinterpret_cast<float4*>(&out[obase]) = r;
    }
}

extern "C" void kernel_launch(void* const* d_in, const int* in_sizes, int n_in,
                              void* d_out, int out_size, void* d_ws, size_t ws_size,
                              hipStream_t stream) {
    const float* feat    = (const float*)d_in[0];   // (N, 2)
    const float* weight  = (const float*)d_in[1];   // (27, 2, 64)
    const float* gamma   = (const float*)d_in[2];   // (64,)
    const float* beta    = (const float*)d_in[3];   // (64,)
    const int*   scatter = (const int*)d_in[4];     // (27, N)
    float* out = (float*)d_out;                     // (CELLS, 64)

    int* map = (int*)d_ws;                          // CELLS * 4 B = 3.84 MB

    hipMemsetAsync(map, 0xFF, (size_t)CELLS_ * sizeof(int), stream);
    {
        int block = 256;
        int grid = (N_ + block - 1) / block;
        fill_map_kernel<<<grid, block, 0, stream>>>(scatter, map);
    }

    // fused gather-conv + LN + ReLU: 16 cells per 256-thread block
    {
        dim3 block(256, 1, 1);
        dim3 grid((W_ + 15) / 16, H_, B_ * D_);     // 13 x 200 x 24
        gather_cell16_kernel<<<grid, block, 0, stream>>>(feat, weight, gamma,
                                                         beta, map, out);
    }
}